// Round 6
// baseline (416.834 us; speedup 1.0000x reference)
//
#include <hip/hip_runtime.h>

// MSD via MFMA: msd[td] = (1/(180*1536)) * sum_i sum_e (x[100i+td,e]-x[100i,e])^2
//             = (1/(180*1536)) * sum_i ( S[t] + S[100i] - 2*C[t,100i] ),  t=100i+td
// S[t] = sum_e x[t,e]^2 (exact fp32, from the same loads); C = banded GEMM via
// bf16 MFMA 16x16x32 (fp32 accumulate; bf16 error ~1e-4 << 4e-2 threshold).
//
// R4/R5 lesson: broadcast-origin ds_read_b128 costs the full LDS crossbar per
// 16 B of unique data (~47 us of LDS pipe at CU level). MFMA's B-fragment IS
// the origin broadcast, for free. No LDS staging: A and B frags load straight
// from global (per 16-row tile, quads 0..3 of a row cover one contiguous
// 128 B line across the two dwordx4 loads -> full line utilization).
//
// Block <-> (128-frame tile, K-chunk of 192). Wave w: frames [32w,32w+32),
// origins iBase..iBase+31 (window <=21, padded/clamped; invalid pairs dropped
// in epilogue). acc 2x2 tiles of 16x16. Epilogue: one predicated atomic per
// C element: out[t-100i] += (S_c[t] + S_c[i] - 2C) * SCALE.

typedef __attribute__((ext_vector_type(8))) short bf16x8;   // 8 bf16 (4 VGPR)
typedef __attribute__((ext_vector_type(4))) float f32x4;    // MFMA acc

#define ROWF   1536
#define NFRAME 20000
#define NORIG  180
#define WIN    20
#define FB     128
#define NFB    157       // ceil(20000/128); last block clamps t
#define NKC    8         // K split: 1536 = 8 * 192
#define KC     192
#define NKS    6         // 192 / 32
#define SCALE  (1.0f / (1536.0f * 180.0f))

static __device__ __forceinline__ short f2bf(float f) {
    unsigned u = __builtin_bit_cast(unsigned, f);
    u += 0x7fffu + ((u >> 16) & 1u);
    return (short)(u >> 16);
}

static __device__ __forceinline__ bf16x8 pack8(const float4& v0, const float4& v1) {
    bf16x8 r;
    r[0] = f2bf(v0.x); r[1] = f2bf(v0.y); r[2] = f2bf(v0.z); r[3] = f2bf(v0.w);
    r[4] = f2bf(v1.x); r[5] = f2bf(v1.y); r[6] = f2bf(v1.z); r[7] = f2bf(v1.w);
    return r;
}

static __device__ __forceinline__ float sum8sq(const float4& v0, const float4& v1) {
    return v0.x*v0.x + v0.y*v0.y + v0.z*v0.z + v0.w*v0.w
         + v1.x*v1.x + v1.y*v1.y + v1.z*v1.z + v1.w*v1.w;
}

__global__ __launch_bounds__(256)
void msd_mfma_kernel(const float* __restrict__ x, float* __restrict__ out) {
    __shared__ float sS[FB];   // per-local-frame S-chunk
    __shared__ float sO[32];   // per-origin-slot S-chunk

    const int fb   = blockIdx.x / NKC;     // frame block
    const int kc   = blockIdx.x % NKC;     // K chunk
    const int t0   = fb * FB;
    const int lane = threadIdx.x & 63;
    const int w    = threadIdx.x >> 6;     // wave 0..3

    const int cmin  = t0 / 100;
    int iBase = cmin - (WIN - 1); if (iBase < 0) iBase = 0;

    const int m    = lane & 15;            // row-in-tile (A) / col (B) index
    const int quad = lane >> 4;            // k sub-offset selector
    const int kofs = kc * KC + quad * 8;   // this lane's k start within row

    f32x4 acc[2][2] = {};                  // [m-tile][n-tile]
    float sA[2] = {0.f, 0.f};
    float sB[2] = {0.f, 0.f};

    // clamped global rows for this lane's A (frames) and B (origins)
    int tRow[2], iIdx[2];
    #pragma unroll
    for (int mt = 0; mt < 2; ++mt) {
        int t = t0 + 32 * w + 16 * mt + m;
        tRow[mt] = (t < NFRAME) ? t : (NFRAME - 1);
    }
    #pragma unroll
    for (int nt = 0; nt < 2; ++nt) {
        int i = iBase + 16 * nt + m;
        iIdx[nt] = (i < NORIG) ? i : (NORIG - 1);
    }

    #pragma unroll 1
    for (int ks = 0; ks < NKS; ++ks) {
        const int kk = kofs + ks * 32;
        bf16x8 aF[2], bF[2];
        #pragma unroll
        for (int mt = 0; mt < 2; ++mt) {
            const float* p = x + (size_t)tRow[mt] * ROWF + kk;
            const float4 v0 = *(const float4*)p;
            const float4 v1 = *(const float4*)(p + 4);
            sA[mt] += sum8sq(v0, v1);
            aF[mt] = pack8(v0, v1);
        }
        #pragma unroll
        for (int nt = 0; nt < 2; ++nt) {
            const float* p = x + (size_t)(iIdx[nt] * 100) * ROWF + kk;
            const float4 v0 = *(const float4*)p;
            const float4 v1 = *(const float4*)(p + 4);
            sB[nt] += sum8sq(v0, v1);
            bF[nt] = pack8(v0, v1);
        }
        acc[0][0] = __builtin_amdgcn_mfma_f32_16x16x32_bf16(aF[0], bF[0], acc[0][0], 0, 0, 0);
        acc[0][1] = __builtin_amdgcn_mfma_f32_16x16x32_bf16(aF[0], bF[1], acc[0][1], 0, 0, 0);
        acc[1][0] = __builtin_amdgcn_mfma_f32_16x16x32_bf16(aF[1], bF[0], acc[1][0], 0, 0, 0);
        acc[1][1] = __builtin_amdgcn_mfma_f32_16x16x32_bf16(aF[1], bF[1], acc[1][1], 0, 0, 0);
    }

    // reduce S partials across the 4 quads (lanes m, m+16, m+32, m+48)
    #pragma unroll
    for (int j = 0; j < 2; ++j) {
        sA[j] += __shfl_xor(sA[j], 16, 64);
        sA[j] += __shfl_xor(sA[j], 32, 64);
        sB[j] += __shfl_xor(sB[j], 16, 64);
        sB[j] += __shfl_xor(sB[j], 32, 64);
    }
    if (lane < 16) {
        sS[32 * w + m]      = sA[0];
        sS[32 * w + 16 + m] = sA[1];
        if (w == 0) { sO[m] = sB[0]; sO[16 + m] = sB[1]; }
    }
    __syncthreads();

    // epilogue: C/D layout col = lane&15 (origin), row = quad*4 + reg (frame)
    #pragma unroll
    for (int mt = 0; mt < 2; ++mt) {
        #pragma unroll
        for (int nt = 0; nt < 2; ++nt) {
            #pragma unroll
            for (int r = 0; r < 4; ++r) {
                const int fl = 32 * w + 16 * mt + quad * 4 + r;  // local frame
                const int t  = t0 + fl;
                const int i  = iBase + 16 * nt + m;              // origin idx
                const int c  = t / 100;
                if (t < NFRAME && i < NORIG && i <= c && i >= c - (WIN - 1)) {
                    const float val = sS[fl] + sO[16 * nt + m] - 2.0f * acc[mt][nt][r];
                    atomicAdd(&out[t - 100 * i], val * SCALE);
                }
            }
        }
    }
}

extern "C" void kernel_launch(void* const* d_in, const int* in_sizes, int n_in,
                              void* d_out, int out_size, void* d_ws, size_t ws_size,
                              hipStream_t stream) {
    const float* x = (const float*)d_in[0];
    float* out = (float*)d_out;

    hipMemsetAsync(out, 0, 2000 * sizeof(float), stream);
    msd_mfma_kernel<<<NFB * NKC, 256, 0, stream>>>(x, out);
}

// Round 7
// 210.533 us; speedup vs baseline: 1.9799x; 1.9799x over previous
//
#include <hip/hip_runtime.h>

// MSD via MFMA, atomic-free epilogue.
// msd[td] = (1/(180*1536)) * sum_i ( S[t] + S[100i] - 2*<x[t],x[100i]> ), t=100i+td
//
// R6 post-mortem: 1.75M device atomics onto 2000 words (63 lines) serialized at
// the L2/fabric RMW point (~165 us per M atomics empirically across R2/R4/R6).
// Fix: block <-> 32 frames, FULL K=1536. Since FB=32 < 100, td = t-100i is
// UNIQUE within a block -> each valid (t,i) value goes to a private workspace
// slot ws[b][k*32 + j] (k = t/100 - i in [0,20), j = t-32b) via plain stores.
// Reduce kernel enumerates exactly the valid slots (t = 100i+td, i<180), so
// unwritten slots are never read. ws usage: 625*640*4 = 1.6 MB.
//
// Wave tile: 16 frames x 16 origins, mfma_f32_16x16x32_bf16, 48 K-steps.
// S-terms kept in exact fp32 from the same loads; only the cross term is bf16
// (R6 validated: absmax 7.8e-3 << 4e-2 threshold).

typedef __attribute__((ext_vector_type(8))) short bf16x8;
typedef __attribute__((ext_vector_type(4))) float f32x4;

#define ROWF   1536
#define NFRAME 20000
#define NORIG  180
#define WIN    20
#define FB     32
#define NFB    625      // 625*32 = 20000 exactly
#define NKS    48       // 1536 / 32
#define SLOTS  640      // WIN * FB
#define TDMAX  2000
#define SCALE  (1.0f / (1536.0f * 180.0f))

static __device__ __forceinline__ short f2bf(float f) {
    unsigned u = __builtin_bit_cast(unsigned, f);
    u += 0x7fffu + ((u >> 16) & 1u);
    return (short)(u >> 16);
}

static __device__ __forceinline__ bf16x8 pack8(const float4& v0, const float4& v1) {
    bf16x8 r;
    r[0] = f2bf(v0.x); r[1] = f2bf(v0.y); r[2] = f2bf(v0.z); r[3] = f2bf(v0.w);
    r[4] = f2bf(v1.x); r[5] = f2bf(v1.y); r[6] = f2bf(v1.z); r[7] = f2bf(v1.w);
    return r;
}

static __device__ __forceinline__ float sum8sq(const float4& v0, const float4& v1) {
    return v0.x*v0.x + v0.y*v0.y + v0.z*v0.z + v0.w*v0.w
         + v1.x*v1.x + v1.y*v1.y + v1.z*v1.z + v1.w*v1.w;
}

__global__ __launch_bounds__(256)
void msd_dot_kernel(const float* __restrict__ x, float* __restrict__ ws) {
    __shared__ float sS[FB];   // S[t] for the block's 32 frames
    __shared__ float sO[32];   // S[100i] for the 32 origin slots

    const int b    = blockIdx.x;
    const int t0   = b * FB;
    const int lane = threadIdx.x & 63;
    const int w    = threadIdx.x >> 6;   // 4 waves
    const int mt   = w >> 1;             // frame half (16 frames)
    const int nt   = w & 1;              // origin half (16 slots)
    const int m    = lane & 15;
    const int quad = lane >> 4;

    const int cmin = t0 / 100;
    int iBase = cmin - (WIN - 1); if (iBase < 0) iBase = 0;

    const int t    = t0 + 16 * mt + m;                 // A row (always < 20000)
    const int iNom = iBase + 16 * nt + m;              // B origin, nominal
    const int iClp = (iNom < NORIG) ? iNom : (NORIG - 1);

    const float* pA = x + (size_t)t * ROWF + quad * 8;
    const float* pB = x + (size_t)(iClp * 100) * ROWF + quad * 8;

    f32x4 acc = {};
    float sAp = 0.0f, sBp = 0.0f;

    #pragma unroll 2
    for (int ks = 0; ks < NKS; ++ks) {
        const float4 a0 = *(const float4*)(pA + ks * 32);
        const float4 a1 = *(const float4*)(pA + ks * 32 + 4);
        const float4 b0 = *(const float4*)(pB + ks * 32);
        const float4 b1 = *(const float4*)(pB + ks * 32 + 4);
        sAp += sum8sq(a0, a1);
        sBp += sum8sq(b0, b1);
        acc = __builtin_amdgcn_mfma_f32_16x16x32_bf16(pack8(a0, a1), pack8(b0, b1),
                                                      acc, 0, 0, 0);
    }

    // full-row S: reduce the 4 quad-partials (lanes m, m+16, m+32, m+48)
    sAp += __shfl_xor(sAp, 16, 64); sAp += __shfl_xor(sAp, 32, 64);
    sBp += __shfl_xor(sBp, 16, 64); sBp += __shfl_xor(sBp, 32, 64);
    if (lane < 16) { sS[16 * mt + m] = sAp; sO[16 * nt + m] = sBp; }
    __syncthreads();

    // C/D layout: col = lane&15 (origin slot), row = quad*4 + r (frame-in-tile)
    float* wsb = ws + (size_t)b * SLOTS;
    #pragma unroll
    for (int r = 0; r < 4; ++r) {
        const int j  = 16 * mt + quad * 4 + r;     // frame within block
        const int tt = t0 + j;
        const int c  = tt / 100;
        const int i  = iBase + 16 * nt + m;        // nominal origin of this col
        const int k  = c - i;
        if (k >= 0 && k < WIN && i < NORIG) {
            wsb[k * FB + j] = sS[j] + sO[16 * nt + m] - 2.0f * acc[r];
        }
    }
}

__global__ __launch_bounds__(256)
void msd_reduce_kernel(const float* __restrict__ ws, float* __restrict__ out) {
    const int td = blockIdx.x * 256 + threadIdx.x;
    if (td >= TDMAX) return;
    const int k  = td / 100;
    float acc = 0.0f;
    for (int i = 0; i < NORIG; ++i) {
        const int t = 100 * i + td;                // < 20000 always
        acc += ws[(size_t)(t >> 5) * SLOTS + k * FB + (t & 31)];
    }
    out[td] = acc * SCALE;
}

extern "C" void kernel_launch(void* const* d_in, const int* in_sizes, int n_in,
                              void* d_out, int out_size, void* d_ws, size_t ws_size,
                              hipStream_t stream) {
    const float* x = (const float*)d_in[0];
    float* out = (float*)d_out;
    float* ws  = (float*)d_ws;    // needs 625*640*4 = 1.6 MB

    msd_dot_kernel<<<NFB, 256, 0, stream>>>(x, ws);
    msd_reduce_kernel<<<(TDMAX + 255) / 256, 256, 0, stream>>>(ws, out);
}

// Round 8
// 203.107 us; speedup vs baseline: 2.0523x; 1.0366x over previous
//
#include <hip/hip_runtime.h>

// MSD via MFMA, atomic-free, K-split x2 + deep unroll.
// msd[td] = (1/(180*1536)) * sum_i ( S[t] + S[100i] - 2*<x[t],x[100i]> ), t=100i+td
//
// R7 post-mortem: dot kernel latency-bound (VALUBusy 17%, occ 22%, VGPR 24 --
// compiler kept ~2 K-iters in flight over 625 blocks); reduce kernel had 8
// blocks x 180 serial L2 gathers (~60+ us). Fix: (a) split K into 2 planes of
// 768 -> 1250 blocks (2x occupancy), partial S folded per plane so plane sums
// add exactly; (b) #pragma unroll 4 on the ks loop (16 outstanding dwordx4);
// (c) reduce = 2000 blocks x 1 wave, ~6 strided loads/lane + butterfly.
//
// Block <-> (32 frames, K-plane). FB=32 < 100 makes td unique per block ->
// plain stores into private ws slots; reduce enumerates exactly the valid
// slots. ws usage: 1250 * 640 * 4 = 3.2 MB. bf16 cross term only
// (absmax 7.8e-3 << 4e-2 threshold, validated R6/R7).

typedef __attribute__((ext_vector_type(8))) short bf16x8;
typedef __attribute__((ext_vector_type(4))) float f32x4;

#define ROWF   1536
#define NFRAME 20000
#define NORIG  180
#define WIN    20
#define FB     32
#define NFB    625      // 625*32 = 20000 exactly
#define NKC    2        // K planes
#define KC     768
#define NKS    24       // 768 / 32
#define SLOTS  640      // WIN * FB
#define TDMAX  2000
#define SCALE  (1.0f / (1536.0f * 180.0f))

static __device__ __forceinline__ short f2bf(float f) {
    unsigned u = __builtin_bit_cast(unsigned, f);
    u += 0x7fffu + ((u >> 16) & 1u);
    return (short)(u >> 16);
}

static __device__ __forceinline__ bf16x8 pack8(const float4& v0, const float4& v1) {
    bf16x8 r;
    r[0] = f2bf(v0.x); r[1] = f2bf(v0.y); r[2] = f2bf(v0.z); r[3] = f2bf(v0.w);
    r[4] = f2bf(v1.x); r[5] = f2bf(v1.y); r[6] = f2bf(v1.z); r[7] = f2bf(v1.w);
    return r;
}

static __device__ __forceinline__ float sum8sq(const float4& v0, const float4& v1) {
    return v0.x*v0.x + v0.y*v0.y + v0.z*v0.z + v0.w*v0.w
         + v1.x*v1.x + v1.y*v1.y + v1.z*v1.z + v1.w*v1.w;
}

__global__ __launch_bounds__(256)
void msd_dot_kernel(const float* __restrict__ x, float* __restrict__ ws) {
    __shared__ float sS[FB];   // S-plane-partial for the block's 32 frames
    __shared__ float sO[32];   // S-plane-partial for the 32 origin slots

    const int fb   = blockIdx.x >> 1;    // frame block
    const int kc   = blockIdx.x & 1;     // K plane
    const int t0   = fb * FB;
    const int lane = threadIdx.x & 63;
    const int w    = threadIdx.x >> 6;   // 4 waves
    const int mt   = w >> 1;             // frame half (16 frames)
    const int nt   = w & 1;              // origin half (16 slots)
    const int m    = lane & 15;
    const int quad = lane >> 4;

    const int cmin = t0 / 100;
    int iBase = cmin - (WIN - 1); if (iBase < 0) iBase = 0;

    const int t    = t0 + 16 * mt + m;                 // A row (< 20000 always)
    const int iNom = iBase + 16 * nt + m;              // B origin, nominal
    const int iClp = (iNom < NORIG) ? iNom : (NORIG - 1);

    const float* pA = x + (size_t)t * ROWF + kc * KC + quad * 8;
    const float* pB = x + (size_t)(iClp * 100) * ROWF + kc * KC + quad * 8;

    f32x4 acc = {};
    float sAp = 0.0f, sBp = 0.0f;

    #pragma unroll 4
    for (int ks = 0; ks < NKS; ++ks) {
        const float4 a0 = *(const float4*)(pA + ks * 32);
        const float4 a1 = *(const float4*)(pA + ks * 32 + 4);
        const float4 b0 = *(const float4*)(pB + ks * 32);
        const float4 b1 = *(const float4*)(pB + ks * 32 + 4);
        sAp += sum8sq(a0, a1);
        sBp += sum8sq(b0, b1);
        acc = __builtin_amdgcn_mfma_f32_16x16x32_bf16(pack8(a0, a1), pack8(b0, b1),
                                                      acc, 0, 0, 0);
    }

    // plane-partial S per row: reduce the 4 quad-partials
    sAp += __shfl_xor(sAp, 16, 64); sAp += __shfl_xor(sAp, 32, 64);
    sBp += __shfl_xor(sBp, 16, 64); sBp += __shfl_xor(sBp, 32, 64);
    if (lane < 16) { sS[16 * mt + m] = sAp; sO[16 * nt + m] = sBp; }
    __syncthreads();

    // C/D layout: col = lane&15 (origin slot), row = quad*4 + r (frame-in-tile)
    float* wsb = ws + (size_t)blockIdx.x * SLOTS;
    #pragma unroll
    for (int r = 0; r < 4; ++r) {
        const int j  = 16 * mt + quad * 4 + r;     // frame within block
        const int tt = t0 + j;
        const int c  = tt / 100;
        const int i  = iBase + 16 * nt + m;        // nominal origin of this col
        const int k  = c - i;
        if (k >= 0 && k < WIN && i < NORIG) {
            wsb[k * FB + j] = sS[j] + sO[16 * nt + m] - 2.0f * acc[r];
        }
    }
}

__global__ __launch_bounds__(64)
void msd_reduce_kernel(const float* __restrict__ ws, float* __restrict__ out) {
    const int td   = blockIdx.x;          // 0..1999
    const int lane = threadIdx.x;         // 0..63
    const int k    = td / 100;

    float acc = 0.0f;
    #pragma unroll 1
    for (int i = lane; i < NORIG; i += 64) {
        const int t  = 100 * i + td;                  // < 20000 always
        const int fb = t >> 5;
        const int sl = k * FB + (t & 31);
        acc += ws[(size_t)(fb * 2 + 0) * SLOTS + sl];
        acc += ws[(size_t)(fb * 2 + 1) * SLOTS + sl];
    }
    #pragma unroll
    for (int off = 32; off >= 1; off >>= 1)
        acc += __shfl_xor(acc, off, 64);
    if (lane == 0) out[td] = acc * SCALE;
}

extern "C" void kernel_launch(void* const* d_in, const int* in_sizes, int n_in,
                              void* d_out, int out_size, void* d_ws, size_t ws_size,
                              hipStream_t stream) {
    const float* x = (const float*)d_in[0];
    float* out = (float*)d_out;
    float* ws  = (float*)d_ws;    // needs 1250*640*4 = 3.2 MB

    msd_dot_kernel<<<NFB * NKC, 256, 0, stream>>>(x, ws);
    msd_reduce_kernel<<<TDMAX, 64, 0, stream>>>(ws, out);
}